// Round 1
// baseline (1026.489 us; speedup 1.0000x reference)
//
#include <hip/hip_runtime.h>
#include <math.h>

// FNOBlock: out = v + irfft( modemix( rfft(v)[:, :512] ), n=4096 )
// B=32, N=4096, C=256, M=512.
// Pipeline:
//   K1 fwd_fft : per (b, channel-pair) 4096-pt complex FFT (2 real channels packed),
//                DIF natural-in/bitrev-out, unpack modes 0..511 -> fm planes in ws
//   K2 mode_mix: per mode m, gm = X(64x256) @ R[m](256x256), fp32 register-tiled
//   K3 inv_fft : scatter modes (Hermitian pair) to bitrev positions, DIT iFFT,
//                add residual v, write out.

constexpr int BB = 32;
constexpr int NN = 4096;
constexpr int CC = 256;
constexpr int MM = 512;
constexpr int NPAIR = CC / 2;   // 128 channel pairs
constexpr size_t PLANE = (size_t)MM * BB * CC;  // 4,194,304 floats per plane

// ---------------- K1: forward FFT ----------------
__global__ __launch_bounds__(256) void fwd_fft_kernel(const float* __restrict__ v,
                                                      float* __restrict__ fmre,
                                                      float* __restrict__ fmim) {
    __shared__ float xr[NN];
    __shared__ float xi[NN];
    const int b = blockIdx.x >> 7;     // / 128
    const int p = blockIdx.x & 127;
    const int t = threadIdx.x;

    // pack channels (2p, 2p+1) into complex sequence  (uncoalesced: 8B per 1KB row)
    const float* vb = v + ((size_t)b * NN * CC) + 2 * p;
    for (int n = t; n < NN; n += 256) {
        float2 z = *(const float2*)(vb + (size_t)n * CC);
        xr[n] = z.x; xi[n] = z.y;
    }
    __syncthreads();

    // radix-2 DIF, natural order in -> bit-reversed out. w = exp(-2*pi*i*k/4096)
    const float w0 = -6.28318530717958647692f / 4096.0f;
    for (int s = 0; s < 12; ++s) {
        const int hs = 11 - s;               // log2(half)
        for (int it = 0; it < 8; ++it) {
            int idx = t + (it << 8);          // 0..2047
            int j   = idx & ((1 << hs) - 1);
            int blk = idx >> hs;
            int i0  = (blk << (hs + 1)) + j;
            int i1  = i0 + (1 << hs);
            float ar = xr[i0], ai = xi[i0];
            float br = xr[i1], bi = xi[i1];
            float sr = ar + br, si = ai + bi;
            float dr = ar - br, di = ai - bi;
            int k = j << s;
            float ws, wc;
            __sincosf(w0 * (float)k, &ws, &wc);
            xr[i0] = sr; xi[i0] = si;
            xr[i1] = dr * wc - di * ws;
            xi[i1] = dr * ws + di * wc;
        }
        __syncthreads();
    }

    // unpack: F0 = 0.5(Z[k]+conj(Z[N-k])), F1 = -0.5i(Z[k]-conj(Z[N-k]))
    for (int k = t; k < MM; k += 256) {
        int rk  = __brev((unsigned)k) >> 20;                      // bitrev12
        int rnk = __brev((unsigned)((NN - k) & (NN - 1))) >> 20;
        float zr = xr[rk],  zi = xi[rk];
        float cr = xr[rnk], ci = xi[rnk];
        float f0r = 0.5f * (zr + cr);
        float f0i = 0.5f * (zi - ci);
        float f1r = 0.5f * (zi + ci);
        float f1i = 0.5f * (cr - zr);
        size_t o = ((size_t)k * BB + b) * CC + 2 * p;   // fm[m][b][c]
        *(float2*)(fmre + o) = make_float2(f0r, f1r);
        *(float2*)(fmim + o) = make_float2(f0i, f1i);
    }
}

// ---------------- K2: per-mode channel mix ----------------
// gm[b,m,o] = sum_i R[m,i,o] * fm[b,m,i]  (R real; Re/Im rows independent)
__global__ __launch_bounds__(256) void mode_mix_kernel(const float* __restrict__ fmre,
                                                       const float* __restrict__ fmim,
                                                       const float* __restrict__ R,
                                                       float* __restrict__ gmre,
                                                       float* __restrict__ gmim) {
    __shared__ float XT[256 * 64];   // [i][r]  r: 0..31 Re(b), 32..63 Im(b)  (64 KB)
    const int m = blockIdx.x;
    const int t = threadIdx.x;
    {
        int b  = t >> 3;
        int i0 = (t & 7) * 32;
        const float* pr = fmre + ((size_t)m * BB + b) * CC + i0;
        const float* pi = fmim + ((size_t)m * BB + b) * CC + i0;
        #pragma unroll 8
        for (int q = 0; q < 32; ++q) {
            XT[(i0 + q) * 64 + b]      = pr[q];
            XT[(i0 + q) * 64 + 32 + b] = pi[q];
        }
    }
    __syncthreads();

    const int rblk = t >> 4;   // 16 row-blocks of 4
    const int ol   = t & 15;
    float4 acc[4][4];          // [o-tile j][row rr] -> 4 o's
    #pragma unroll
    for (int jj = 0; jj < 4; ++jj)
        #pragma unroll
        for (int rr = 0; rr < 4; ++rr) acc[jj][rr] = make_float4(0.f, 0.f, 0.f, 0.f);

    const float* Rb = R + (size_t)m * CC * CC;
    for (int i = 0; i < CC; ++i) {
        float4 xv = *(const float4*)&XT[i * 64 + rblk * 4];
        #pragma unroll
        for (int jj = 0; jj < 4; ++jj) {
            float4 rv = *(const float4*)&Rb[i * CC + (ol + 16 * jj) * 4];
            acc[jj][0].x += xv.x * rv.x; acc[jj][0].y += xv.x * rv.y; acc[jj][0].z += xv.x * rv.z; acc[jj][0].w += xv.x * rv.w;
            acc[jj][1].x += xv.y * rv.x; acc[jj][1].y += xv.y * rv.y; acc[jj][1].z += xv.y * rv.z; acc[jj][1].w += xv.y * rv.w;
            acc[jj][2].x += xv.z * rv.x; acc[jj][2].y += xv.z * rv.y; acc[jj][2].z += xv.z * rv.z; acc[jj][2].w += xv.z * rv.w;
            acc[jj][3].x += xv.w * rv.x; acc[jj][3].y += xv.w * rv.y; acc[jj][3].z += xv.w * rv.z; acc[jj][3].w += xv.w * rv.w;
        }
    }

    #pragma unroll
    for (int jj = 0; jj < 4; ++jj) {
        int o0 = (ol + 16 * jj) * 4;
        #pragma unroll
        for (int rr = 0; rr < 4; ++rr) {
            int r = rblk * 4 + rr;
            float* dst = (r < 32) ? (gmre + ((size_t)m * BB + r) * CC + o0)
                                  : (gmim + ((size_t)m * BB + (r - 32)) * CC + o0);
            *(float4*)dst = acc[jj][rr];
        }
    }
}

// ---------------- K3: inverse FFT + residual ----------------
__global__ __launch_bounds__(256) void inv_fft_kernel(const float* __restrict__ gmre,
                                                      const float* __restrict__ gmim,
                                                      const float* __restrict__ v,
                                                      float* __restrict__ out) {
    __shared__ float xr[NN];
    __shared__ float xi[NN];
    const int b = blockIdx.x >> 7;
    const int p = blockIdx.x & 127;
    const int t = threadIdx.x;

    for (int n = t; n < NN; n += 256) { xr[n] = 0.f; xi[n] = 0.f; }
    __syncthreads();

    // scatter: Z[k] = G0 + i*G1 ; Z[N-k] = conj(G0) + i*conj(G1)  at bitrev positions
    for (int k = t; k < MM; k += 256) {
        size_t o = ((size_t)k * BB + b) * CC + 2 * p;
        float2 gr = *(const float2*)(gmre + o);   // (G0r, G1r)
        float2 gi = *(const float2*)(gmim + o);   // (G0i, G1i)
        int rk = __brev((unsigned)k) >> 20;
        xr[rk] = gr.x - gi.y;
        xi[rk] = gi.x + gr.y;
        if (k > 0) {
            int rnk = __brev((unsigned)(NN - k)) >> 20;
            xr[rnk] = gr.x + gi.y;
            xi[rnk] = gr.y - gi.x;
        }
    }
    __syncthreads();

    // radix-2 DIT, bit-reversed in -> natural out. w = exp(+2*pi*i*k/4096)
    const float w0 = 6.28318530717958647692f / 4096.0f;
    for (int s = 0; s < 12; ++s) {
        for (int it = 0; it < 8; ++it) {
            int idx = t + (it << 8);
            int j   = idx & ((1 << s) - 1);
            int blk = idx >> s;
            int i0  = (blk << (s + 1)) + j;
            int i1  = i0 + (1 << s);
            int k   = j << (11 - s);
            float ws, wc;
            __sincosf(w0 * (float)k, &ws, &wc);
            float xr1 = xr[i1], xi1 = xi[i1];
            float br = xr1 * wc - xi1 * ws;
            float bi = xr1 * ws + xi1 * wc;
            float ar = xr[i0], ai = xi[i0];
            xr[i0] = ar + br; xi[i0] = ai + bi;
            xr[i1] = ar - br; xi[i1] = ai - bi;
        }
        __syncthreads();
    }

    const float inv_n = 1.0f / 4096.0f;
    const float* vb = v   + ((size_t)b * NN * CC) + 2 * p;
    float*       ob = out + ((size_t)b * NN * CC) + 2 * p;
    for (int n = t; n < NN; n += 256) {
        float2 vz = *(const float2*)(vb + (size_t)n * CC);
        float2 r;
        r.x = vz.x + xr[n] * inv_n;
        r.y = vz.y + xi[n] * inv_n;
        *(float2*)(ob + (size_t)n * CC) = r;
    }
}

extern "C" void kernel_launch(void* const* d_in, const int* in_sizes, int n_in,
                              void* d_out, int out_size, void* d_ws, size_t ws_size,
                              hipStream_t stream) {
    const float* v = (const float*)d_in[0];
    const float* R = (const float*)d_in[1];
    float* out = (float*)d_out;

    float* fmre = (float*)d_ws;          // [512][32][256]
    float* fmim = fmre + PLANE;
    float* gmre = fmim + PLANE;
    float* gmim = gmre + PLANE;          // total 64 MiB of ws

    fwd_fft_kernel<<<BB * NPAIR, 256, 0, stream>>>(v, fmre, fmim);
    mode_mix_kernel<<<MM, 256, 0, stream>>>(fmre, fmim, R, gmre, gmim);
    inv_fft_kernel<<<BB * NPAIR, 256, 0, stream>>>(gmre, gmim, v, out);
}

// Round 2
// 546.726 us; speedup vs baseline: 1.8775x; 1.8775x over previous
//
#include <hip/hip_runtime.h>
#include <hip/hip_fp16.h>
#include <math.h>

// FNOBlock via four-step FFT (4096 = 64 x 64), all global accesses >=256B chunks.
// K1a: FFT64 over n1 (per n2), twiddle, -> ybuf (fp16, [bl][k1][n2][pair])
// K1b: FFT64 over n2 (per k1), -> zbuf packed modes (fp16, [b][k1][j16][pair])
// K2 : per-mode GEMM, Hermitian unpack inline from zbuf, -> gm fp16 planes
// K3a: build Z from gm (direct + conj rows), iFFT64 over k2, twiddle -> tbuf
// K3b: iFFT64 over k1, + residual v, write out.
// ws = 33.5MB (ybuf/tbuf, half the batch, 2 passes) + 16.8MB zbuf + 16.8MB gm = 64 MiB.

constexpr int BB = 32;
constexpr int NN = 4096;
constexpr int CC = 256;
constexpr int MM = 512;

#define STR 65   // LDS row stride (pad 64+1): FFT accesses are <=2-way conflicts (free)

__device__ __forceinline__ int rev6(int x) { return (int)(__brev((unsigned)x) >> 26); }

// 64 sequences x 64 complex points in LDS. DIF radix-2, natural-in, bitrev-out.
// sgn=+1: forward (e^{-i}), sgn=-1: inverse (e^{+i}). 256 threads.
__device__ __forceinline__ void fft64_lds(float* xr, float* xi, int t, float sgn) {
    const int bf = t & 31;
    const int sbase = t >> 5;
    #pragma unroll
    for (int st = 0; st < 6; ++st) {
        const int l2 = 5 - st;
        const int h  = 1 << l2;
        const int j  = bf & (h - 1);
        const int i0 = ((bf >> l2) << (l2 + 1)) + j;
        const int i1 = i0 + h;
        float ws, wc;
        __sincosf(sgn * (-0.09817477042468103f) * (float)(j << st), &ws, &wc);  // -2pi/64
        #pragma unroll
        for (int q = 0; q < 8; ++q) {
            float* rr = xr + (sbase + 8 * q) * STR;
            float* ii = xi + (sbase + 8 * q) * STR;
            float ar = rr[i0], ai = ii[i0];
            float br = rr[i1], bi = ii[i1];
            float dr = ar - br, di = ai - bi;
            rr[i0] = ar + br; ii[i0] = ai + bi;
            rr[i1] = dr * wc - di * ws;
            ii[i1] = dr * ws + di * wc;
        }
        __syncthreads();
    }
}

// ---------------- K1a ----------------
__global__ __launch_bounds__(256) void k1a_kernel(const float* __restrict__ v,
                                                  __half2* __restrict__ ybuf, int b0) {
    __shared__ float xr[64 * STR], xi[64 * STR];
    const int blk = blockIdx.x;
    const int ct = blk & 1;
    const int n2 = (blk >> 1) & 63;
    const int bl = blk >> 7;           // 0..15 (local batch)
    const int b  = b0 + bl;
    const int t = threadIdx.x;
    const int p = t & 63;              // pair within 64-pair tile
    const int g = t >> 6;
    const int c0 = ct * 128;

    // load rows n = 64*n1 + n2, channels c0..c0+127 packed as pairs (512B/row)
    const float* vb = v + ((size_t)b << 20) + (size_t)n2 * CC + c0 + 2 * p;
    #pragma unroll
    for (int q = 0; q < 16; ++q) {
        int n1 = g + 4 * q;
        float2 z = *(const float2*)(vb + (size_t)n1 * 64 * CC);
        xr[p * STR + n1] = z.x;
        xi[p * STR + n1] = z.y;
    }
    __syncthreads();
    fft64_lds(xr, xi, t, 1.0f);

    // twiddle W_4096^{n2*k1}, store [bl][k1][n2][pair]
    __half2* yb = ybuf + (size_t)bl * (64 * 64 * 128) + ct * 64 + p;
    #pragma unroll
    for (int q = 0; q < 16; ++q) {
        int pos = g + 4 * q;
        int k1 = rev6(pos);
        float ws, wc;
        __sincosf(-1.5339807878856412e-3f * (float)(n2 * k1), &ws, &wc);  // -2pi/4096
        float re = xr[p * STR + pos], im = xi[p * STR + pos];
        yb[(size_t)(k1 * 64 + n2) * 128] = __floats2half2_rn(re * wc - im * ws, re * ws + im * wc);
    }
}

// ---------------- K1b ----------------
__global__ __launch_bounds__(256) void k1b_kernel(const __half2* __restrict__ ybuf,
                                                  __half2* __restrict__ zbuf, int b0) {
    __shared__ float xr[64 * STR], xi[64 * STR];
    const int blk = blockIdx.x;
    const int ct = blk & 1;
    const int k1 = (blk >> 1) & 63;
    const int bl = blk >> 7;
    const int b  = b0 + bl;
    const int t = threadIdx.x;
    const int p = t & 63;
    const int g = t >> 6;

    const __half2* yb = ybuf + (size_t)bl * (64 * 64 * 128) + (size_t)k1 * (64 * 128) + ct * 64 + p;
    #pragma unroll
    for (int q = 0; q < 16; ++q) {
        int n2 = g + 4 * q;
        float2 z = __half22float2(yb[(size_t)n2 * 128]);
        xr[p * STR + n2] = z.x;
        xi[p * STR + n2] = z.y;
    }
    __syncthreads();
    fft64_lds(xr, xi, t, 1.0f);

    // keep k2 in [0,8) (j=k2) and [56,64) (j=k2-48): Z[k1+64*k2]
    __half2* zb = zbuf + ((size_t)(b * 64 + k1) * 16) * 128 + ct * 64 + p;
    #pragma unroll
    for (int q = 0; q < 4; ++q) {
        int j = g + 4 * q;
        int k2 = (j < 8) ? j : (48 + j);
        int pos = rev6(k2);
        zb[(size_t)j * 128] = __floats2half2_rn(xr[p * STR + pos], xi[p * STR + pos]);
    }
}

// ---------------- K2: per-mode channel mix ----------------
__global__ __launch_bounds__(256) void k2_kernel(const __half2* __restrict__ zbuf,
                                                 const float* __restrict__ R,
                                                 __half* __restrict__ gre,
                                                 __half* __restrict__ gim) {
    __shared__ float XT[256 * 64];   // [i][r] r: 0..31 Re(b), 32..63 Im(b)
    const int m = blockIdx.x;
    const int t = threadIdx.x;
    const int k1 = m & 63, k2 = m >> 6;
    int k1p, jp;
    if (k1 == 0) { k1p = 0;       jp = (k2 == 0) ? 0 : (16 - k2); }
    else         { k1p = 64 - k1; jp = 15 - k2; }
    {
        const int b  = t & 31;
        const int pg = t >> 5;
        const __half2* zm = zbuf + ((size_t)(b * 64 + k1 ) * 16 + k2) * 128;
        const __half2* zp = zbuf + ((size_t)(b * 64 + k1p) * 16 + jp) * 128;
        #pragma unroll
        for (int q = 0; q < 16; ++q) {
            int pp = pg + 8 * q;
            float2 a = __half22float2(zm[pp]);
            float2 c = __half22float2(zp[pp]);
            XT[(2 * pp) * 64 + b]          = 0.5f * (a.x + c.x);   // F0r
            XT[(2 * pp) * 64 + 32 + b]     = 0.5f * (a.y - c.y);   // F0i
            XT[(2 * pp + 1) * 64 + b]      = 0.5f * (a.y + c.y);   // F1r
            XT[(2 * pp + 1) * 64 + 32 + b] = 0.5f * (c.x - a.x);   // F1i
        }
    }
    __syncthreads();

    const int rblk = t >> 4;
    const int ol   = t & 15;
    float4 acc[4][4];
    #pragma unroll
    for (int jj = 0; jj < 4; ++jj)
        #pragma unroll
        for (int rr = 0; rr < 4; ++rr) acc[jj][rr] = make_float4(0.f, 0.f, 0.f, 0.f);

    const float* Rb = R + (size_t)m * CC * CC;
    for (int i = 0; i < CC; ++i) {
        float4 xv = *(const float4*)&XT[i * 64 + rblk * 4];
        #pragma unroll
        for (int jj = 0; jj < 4; ++jj) {
            float4 rv = *(const float4*)&Rb[i * CC + (ol + 16 * jj) * 4];
            acc[jj][0].x += xv.x * rv.x; acc[jj][0].y += xv.x * rv.y; acc[jj][0].z += xv.x * rv.z; acc[jj][0].w += xv.x * rv.w;
            acc[jj][1].x += xv.y * rv.x; acc[jj][1].y += xv.y * rv.y; acc[jj][1].z += xv.y * rv.z; acc[jj][1].w += xv.y * rv.w;
            acc[jj][2].x += xv.z * rv.x; acc[jj][2].y += xv.z * rv.y; acc[jj][2].z += xv.z * rv.z; acc[jj][2].w += xv.z * rv.w;
            acc[jj][3].x += xv.w * rv.x; acc[jj][3].y += xv.w * rv.y; acc[jj][3].z += xv.w * rv.z; acc[jj][3].w += xv.w * rv.w;
        }
    }

    union U { __half2 h2[2]; float2 f2; };
    #pragma unroll
    for (int jj = 0; jj < 4; ++jj) {
        int o0 = (ol + 16 * jj) * 4;
        #pragma unroll
        for (int rr = 0; rr < 4; ++rr) {
            int r = rblk * 4 + rr;
            __half* plane = (r < 32) ? gre : gim;
            size_t off = ((size_t)m * BB + (r & 31)) * CC + o0;
            U u;
            u.h2[0] = __floats2half2_rn(acc[jj][rr].x, acc[jj][rr].y);
            u.h2[1] = __floats2half2_rn(acc[jj][rr].z, acc[jj][rr].w);
            *(float2*)(plane + off) = u.f2;
        }
    }
}

// ---------------- K3a ----------------
__global__ __launch_bounds__(256) void k3a_kernel(const __half* __restrict__ gre,
                                                  const __half* __restrict__ gim,
                                                  __half2* __restrict__ tbuf, int b0) {
    __shared__ float xr[64 * STR], xi[64 * STR];
    const int blk = blockIdx.x;
    const int ct = blk & 1;
    const int k1 = (blk >> 1) & 63;
    const int bl = blk >> 7;
    const int b  = b0 + bl;
    const int t = threadIdx.x;
    const int p = t & 63;
    const int g = t >> 6;
    const int c0 = ct * 128;

    #pragma unroll
    for (int q = 0; q < 16; ++q) { int pos = g + 4 * q; xr[p * STR + pos] = 0.f; xi[p * STR + pos] = 0.f; }
    // direct: k2 in [0,8): Z = G0 + i*G1
    #pragma unroll
    for (int q = 0; q < 2; ++q) {
        int k2 = g + 4 * q;
        int mm = k1 + 64 * k2;
        float2 a = __half22float2(*(const __half2*)(gre + ((size_t)mm * BB + b) * CC + c0 + 2 * p));
        float2 c = __half22float2(*(const __half2*)(gim + ((size_t)mm * BB + b) * CC + c0 + 2 * p));
        xr[p * STR + k2] = a.x - c.y;
        xi[p * STR + k2] = c.x + a.y;
    }
    // conj: k2 in [56,64): Z = conj(G0[mp]) + i*conj(G1[mp])
    #pragma unroll
    for (int q = 0; q < 2; ++q) {
        int k2 = 56 + g + 4 * q;
        int mp = 4096 - k1 - 64 * k2;
        if (mp < 512) {
            float2 a = __half22float2(*(const __half2*)(gre + ((size_t)mp * BB + b) * CC + c0 + 2 * p));
            float2 c = __half22float2(*(const __half2*)(gim + ((size_t)mp * BB + b) * CC + c0 + 2 * p));
            xr[p * STR + k2] = a.x + c.y;
            xi[p * STR + k2] = a.y - c.x;
        }
    }
    __syncthreads();
    fft64_lds(xr, xi, t, -1.0f);

    // twiddle W_4096^{-(-n2*k1)} (inverse sign), store [bl][n2][k1][pair]
    __half2* tb = tbuf + (size_t)bl * (64 * 64 * 128) + (size_t)k1 * 128 + ct * 64 + p;
    #pragma unroll
    for (int q = 0; q < 16; ++q) {
        int pos = g + 4 * q;
        int n2 = rev6(pos);
        float ws, wc;
        __sincosf(1.5339807878856412e-3f * (float)(n2 * k1), &ws, &wc);  // +2pi/4096
        float re = xr[p * STR + pos], im = xi[p * STR + pos];
        tb[(size_t)n2 * (64 * 128)] = __floats2half2_rn(re * wc - im * ws, re * ws + im * wc);
    }
}

// ---------------- K3b ----------------
__global__ __launch_bounds__(256) void k3b_kernel(const __half2* __restrict__ tbuf,
                                                  const float* __restrict__ v,
                                                  float* __restrict__ out, int b0) {
    __shared__ float xr[64 * STR], xi[64 * STR];
    const int blk = blockIdx.x;
    const int ct = blk & 1;
    const int n2 = (blk >> 1) & 63;
    const int bl = blk >> 7;
    const int b  = b0 + bl;
    const int t = threadIdx.x;
    const int p = t & 63;
    const int g = t >> 6;
    const int c0 = ct * 128;

    const __half2* tb = tbuf + (size_t)bl * (64 * 64 * 128) + (size_t)n2 * (64 * 128) + ct * 64 + p;
    #pragma unroll
    for (int q = 0; q < 16; ++q) {
        int k1 = g + 4 * q;
        float2 z = __half22float2(tb[(size_t)k1 * 128]);
        xr[p * STR + k1] = z.x;
        xi[p * STR + k1] = z.y;
    }
    __syncthreads();
    fft64_lds(xr, xi, t, -1.0f);

    const float s = 1.0f / 4096.0f;
    const float* vb = v   + ((size_t)b << 20) + (size_t)n2 * CC + c0 + 2 * p;
    float*       ob = out + ((size_t)b << 20) + (size_t)n2 * CC + c0 + 2 * p;
    #pragma unroll
    for (int q = 0; q < 16; ++q) {
        int pos = g + 4 * q;
        int n1 = rev6(pos);
        size_t off = (size_t)n1 * 64 * CC;   // n = n2 + 64*n1
        float2 vz = *(const float2*)(vb + off);
        float2 r = make_float2(vz.x + xr[p * STR + pos] * s,
                               vz.y + xi[p * STR + pos] * s);
        *(float2*)(ob + off) = r;
    }
}

extern "C" void kernel_launch(void* const* d_in, const int* in_sizes, int n_in,
                              void* d_out, int out_size, void* d_ws, size_t ws_size,
                              hipStream_t stream) {
    const float* v = (const float*)d_in[0];
    const float* R = (const float*)d_in[1];
    float* out = (float*)d_out;

    __half2* ybuf = (__half2*)d_ws;                             // 16*64*64*128 = 33.5 MB (also tbuf)
    __half2* zbuf = ybuf + (size_t)16 * 64 * 64 * 128;          // 32*64*16*128 = 16.8 MB
    __half*  gre  = (__half*)(zbuf + (size_t)32 * 64 * 16 * 128); // 512*32*256  = 8.4 MB
    __half*  gim  = gre + (size_t)MM * BB * CC;                 // 8.4 MB  (total exactly 64 MiB)

    for (int h = 0; h < 2; ++h) {
        k1a_kernel<<<2048, 256, 0, stream>>>(v, ybuf, h * 16);
        k1b_kernel<<<2048, 256, 0, stream>>>(ybuf, zbuf, h * 16);
    }
    k2_kernel<<<MM, 256, 0, stream>>>(zbuf, R, gre, gim);
    for (int h = 0; h < 2; ++h) {
        k3a_kernel<<<2048, 256, 0, stream>>>(gre, gim, ybuf, h * 16);
        k3b_kernel<<<2048, 256, 0, stream>>>(ybuf, v, out, h * 16);
    }
}

// Round 3
// 490.390 us; speedup vs baseline: 2.0932x; 1.1149x over previous
//
#include <hip/hip_runtime.h>
#include <hip/hip_fp16.h>
#include <math.h>

// FNOBlock via four-step FFT (4096 = 64 x 64), register-resident radix-8x8 FFTs.
// K1a: per (b,n2,ctile): FFT64 over n1 (8x8 in regs, LDS transpose), twiddle W4096^{n2 k1} -> ybuf
// K1b: per (b,k1,ctile): FFT64 over n2, keep k2 in {0..7,56..63} -> zbuf
// K2 : per (mode, o-half): 64x256x128 GEMM (fp16 XT in LDS, fp32 acc), Hermitian unpack inline
// K3a: per (b,k1,ctile): pruned iFFT64 over k2 (16 nonzero), twiddle -> tbuf  (no LDS)
// K3b: per (b,n2,ctile): iFFT64 over k1, + residual v -> out

constexpr int BB = 32;
constexpr int CC = 256;
constexpr int MM = 512;

constexpr float PI2_4096 = 1.5339807878856412e-3f;   // 2*pi/4096
constexpr float PI2_512  = 1.2271846303085130e-2f;   // 2*pi/512
constexpr float PI2_64   = 9.8174770424681035e-2f;   // 2*pi/64
constexpr float PI_4     = 0.78539816339744831f;     // 2*pi/8

__device__ __forceinline__ float2 cadd(float2 a, float2 b){ return make_float2(a.x+b.x, a.y+b.y); }
__device__ __forceinline__ float2 csub(float2 a, float2 b){ return make_float2(a.x-b.x, a.y-b.y); }
__device__ __forceinline__ float2 cmulf(float2 a, float2 b){ return make_float2(a.x*b.x - a.y*b.y, a.x*b.y + a.y*b.x); }

// 8-pt DFT, natural order in/out. S=+1: forward (W8=e^{-2pi i/8}); S=-1: inverse (conj twiddles).
template<int S>
__device__ __forceinline__ void dif8(float2 x[8]) {
    const float R = 0.70710678118654752f;
    const float Sf = (float)S;
    float2 a0=cadd(x[0],x[4]), a1=cadd(x[1],x[5]), a2=cadd(x[2],x[6]), a3=cadd(x[3],x[7]);
    float2 d0=csub(x[0],x[4]), d1=csub(x[1],x[5]), d2=csub(x[2],x[6]), d3=csub(x[3],x[7]);
    float2 t5 = cmulf(d1, make_float2(R, -R*Sf));
    float2 t6 = make_float2(Sf*d2.y, -Sf*d2.x);                 // *(-iS)
    float2 t7 = cmulf(d3, make_float2(-R, -R*Sf));
    float2 b0=cadd(a0,a2), b1=cadd(a1,a3), b2=csub(a0,a2), e3=csub(a1,a3);
    float2 b3=make_float2(Sf*e3.y, -Sf*e3.x);
    float2 b4=cadd(d0,t6), b5=cadd(t5,t7), b6=csub(d0,t6), e7=csub(t5,t7);
    float2 b7=make_float2(Sf*e7.y, -Sf*e7.x);
    x[0]=cadd(b0,b1); x[4]=csub(b0,b1);
    x[2]=cadd(b2,b3); x[6]=csub(b2,b3);
    x[1]=cadd(b4,b5); x[5]=csub(b4,b5);
    x[3]=cadd(b6,b7); x[7]=csub(b6,b7);
}

// x[k] *= e^{i*ang*k}, k=1..7 (iterated powers)
__device__ __forceinline__ void twid7(float2 x[8], float ang) {
    float s, c;
    __sincosf(ang, &s, &c);
    float2 w = make_float2(c, s), cur = w;
    x[1] = cmulf(x[1], cur);
    #pragma unroll
    for (int k = 2; k < 8; ++k) { cur = cmulf(cur, w); x[k] = cmulf(x[k], cur); }
}

// ---------------- K1a ----------------
__global__ __launch_bounds__(256) void k1a_kernel(const float* __restrict__ v,
                                                  __half2* __restrict__ ybuf, int b0) {
    __shared__ float2 T[64 * 65];
    const int blk = blockIdx.x;
    const int ct = blk & 1;
    const int n2 = (blk >> 1) & 63;
    const int bl = blk >> 7;
    const int bat = b0 + bl;
    const int t = threadIdx.x;
    const int p = t & 63;
    const int g = t >> 6;

    const float* vb = v + ((size_t)bat << 20) + (size_t)n2 * CC + ct * 128 + 2 * p;
    float2 X[2][8];
    #pragma unroll
    for (int s = 0; s < 2; ++s) {
        const int bd = g + 4 * s;
        #pragma unroll
        for (int a = 0; a < 8; ++a)
            X[s][a] = *(const float2*)(vb + (size_t)(8 * a + bd) * 16384);
    }
    #pragma unroll
    for (int s = 0; s < 2; ++s) {
        const int bd = g + 4 * s;
        dif8<1>(X[s]);
        twid7(X[s], -PI2_64 * (float)bd);          // W64^{bd*k0}
        float2* row = T + p * 65;
        #pragma unroll
        for (int k0 = 0; k0 < 8; ++k0) row[bd + 8 * k0] = X[s][k0];
    }
    __syncthreads();

    __half2* yb = ybuf + (size_t)bl * (64 * 64 * 128) + ct * 64 + p;
    #pragma unroll
    for (int s = 0; s < 2; ++s) {
        const int k0 = g + 4 * s;
        float2 Y[8];
        const float2* row = T + p * 65 + 8 * k0;
        #pragma unroll
        for (int b = 0; b < 8; ++b) Y[b] = row[b];
        dif8<1>(Y);                                 // A[k0 + 8*k1b]
        float bs, bc, ss, sc;
        __sincosf(-PI2_4096 * (float)(n2 * k0), &bs, &bc);
        __sincosf(-PI2_512 * (float)n2, &ss, &sc);
        float2 cur = make_float2(bc, bs), stp = make_float2(sc, ss);
        #pragma unroll
        for (int k1b = 0; k1b < 8; ++k1b) {
            float2 r = cmulf(Y[k1b], cur);
            yb[(size_t)((k0 + 8 * k1b) * 64 + n2) * 128] = __floats2half2_rn(r.x, r.y);
            cur = cmulf(cur, stp);
        }
    }
}

// ---------------- K1b ----------------
__global__ __launch_bounds__(256) void k1b_kernel(const __half2* __restrict__ ybuf,
                                                  __half2* __restrict__ zbuf, int b0) {
    __shared__ float2 T[64 * 65];
    const int blk = blockIdx.x;
    const int ct = blk & 1;
    const int k1 = (blk >> 1) & 63;
    const int bl = blk >> 7;
    const int bat = b0 + bl;
    const int t = threadIdx.x;
    const int p = t & 63;
    const int g = t >> 6;
    const float R = 0.70710678118654752f;

    const __half2* yb = ybuf + (size_t)bl * (64 * 64 * 128) + (size_t)k1 * (64 * 128) + ct * 64 + p;
    float2 X[2][8];
    #pragma unroll
    for (int s = 0; s < 2; ++s) {
        const int bd = g + 4 * s;
        #pragma unroll
        for (int a = 0; a < 8; ++a)
            X[s][a] = __half22float2(yb[(size_t)(8 * a + bd) * 128]);
    }
    #pragma unroll
    for (int s = 0; s < 2; ++s) {
        const int bd = g + 4 * s;
        dif8<1>(X[s]);
        twid7(X[s], -PI2_64 * (float)bd);
        float2* row = T + p * 65;
        #pragma unroll
        for (int k0 = 0; k0 < 8; ++k0) row[bd + 8 * k0] = X[s][k0];
    }
    __syncthreads();

    __half2* zb = zbuf + ((size_t)(bat * 64 + k1) * 16) * 128 + ct * 64 + p;
    #pragma unroll
    for (int s = 0; s < 2; ++s) {
        const int k20 = g + 4 * s;
        float2 r[8];
        const float2* row = T + p * 65 + 8 * k20;
        #pragma unroll
        for (int b = 0; b < 8; ++b) r[b] = row[b];
        // B[k20] = sum r[b];  B[k20+56] = sum r[b]*e^{+i pi b/4}
        float2 sum0 = make_float2(0.f, 0.f);
        #pragma unroll
        for (int b = 0; b < 8; ++b) sum0 = cadd(sum0, r[b]);
        float2 e0 = csub(r[0], r[4]);
        float2 e1 = csub(r[1], r[5]);
        float2 e2 = csub(r[2], r[6]);
        float2 e3 = csub(r[3], r[7]);
        float2 sum7 = cadd(cadd(e0, cmulf(e1, make_float2(R, R))),
                           cadd(make_float2(-e2.y, e2.x), cmulf(e3, make_float2(-R, R))));
        zb[(size_t)k20 * 128]       = __floats2half2_rn(sum0.x, sum0.y);
        zb[(size_t)(k20 + 8) * 128] = __floats2half2_rn(sum7.x, sum7.y);
    }
}

// ---------------- K2: per-(mode, o-half) channel mix ----------------
__global__ __launch_bounds__(256) void k2_kernel(const __half2* __restrict__ zbuf,
                                                 const float* __restrict__ R,
                                                 __half* __restrict__ gre,
                                                 __half* __restrict__ gim) {
    __shared__ __half XT[256 * 64];   // [i][r] fp16; r: 0..31 Re(b), 32..63 Im(b)
    const int mh = blockIdx.x & 1;
    const int m  = blockIdx.x >> 1;
    const int t = threadIdx.x;
    const int k1 = m & 63, k2 = m >> 6;
    int k1p, jp;
    if (k1 == 0) { k1p = 0;       jp = (k2 == 0) ? 0 : (16 - k2); }
    else         { k1p = 64 - k1; jp = 15 - k2; }
    {
        const int b  = t & 31;
        const int pg = t >> 5;
        const __half2* zm = zbuf + ((size_t)(b * 64 + k1 ) * 16 + k2) * 128;
        const __half2* zp = zbuf + ((size_t)(b * 64 + k1p) * 16 + jp) * 128;
        #pragma unroll
        for (int q = 0; q < 16; ++q) {
            int pp = pg + 8 * q;
            float2 a = __half22float2(zm[pp]);
            float2 c = __half22float2(zp[pp]);
            XT[(2 * pp) * 64 + b]          = __float2half_rn(0.5f * (a.x + c.x));
            XT[(2 * pp) * 64 + 32 + b]     = __float2half_rn(0.5f * (a.y - c.y));
            XT[(2 * pp + 1) * 64 + b]      = __float2half_rn(0.5f * (a.y + c.y));
            XT[(2 * pp + 1) * 64 + 32 + b] = __float2half_rn(0.5f * (c.x - a.x));
        }
    }
    __syncthreads();

    const int rblk = t >> 4;
    const int ol   = t & 15;
    float4 acc[2][4];
    #pragma unroll
    for (int jj = 0; jj < 2; ++jj)
        #pragma unroll
        for (int rr = 0; rr < 4; ++rr) acc[jj][rr] = make_float4(0.f, 0.f, 0.f, 0.f);

    const float* Rb = R + (size_t)m * 65536 + mh * 128 + ol * 4;
    float4 c0 = *(const float4*)&Rb[0];
    float4 c1 = *(const float4*)&Rb[64];
    for (int i = 0; i < 256; ++i) {
        float4 n0 = c0, n1 = c1;
        if (i < 255) {
            n0 = *(const float4*)&Rb[(size_t)(i + 1) * 256];
            n1 = *(const float4*)&Rb[(size_t)(i + 1) * 256 + 64];
        }
        const __half2* xp = (const __half2*)&XT[i * 64 + rblk * 4];
        float2 x01 = __half22float2(xp[0]);
        float2 x23 = __half22float2(xp[1]);
        float xs[4] = {x01.x, x01.y, x23.x, x23.y};
        #pragma unroll
        for (int rr = 0; rr < 4; ++rr) {
            acc[0][rr].x += xs[rr] * c0.x; acc[0][rr].y += xs[rr] * c0.y;
            acc[0][rr].z += xs[rr] * c0.z; acc[0][rr].w += xs[rr] * c0.w;
            acc[1][rr].x += xs[rr] * c1.x; acc[1][rr].y += xs[rr] * c1.y;
            acc[1][rr].z += xs[rr] * c1.z; acc[1][rr].w += xs[rr] * c1.w;
        }
        c0 = n0; c1 = n1;
    }

    union U { __half2 h2[2]; float2 f2; };
    #pragma unroll
    for (int jj = 0; jj < 2; ++jj) {
        #pragma unroll
        for (int rr = 0; rr < 4; ++rr) {
            int r = rblk * 4 + rr;
            __half* plane = (r < 32) ? gre : gim;
            size_t off = ((size_t)m * BB + (r & 31)) * CC + mh * 128 + (ol + 16 * jj) * 4;
            U u;
            u.h2[0] = __floats2half2_rn(acc[jj][rr].x, acc[jj][rr].y);
            u.h2[1] = __floats2half2_rn(acc[jj][rr].z, acc[jj][rr].w);
            *(float2*)(plane + off) = u.f2;
        }
    }
}

// ---------------- K3a (no LDS) ----------------
__global__ __launch_bounds__(256) void k3a_kernel(const __half* __restrict__ gre,
                                                  const __half* __restrict__ gim,
                                                  __half2* __restrict__ tbuf, int b0) {
    const int blk = blockIdx.x;
    const int ct = blk & 1;
    const int k1 = (blk >> 1) & 63;
    const int bl = blk >> 7;
    const int bat = b0 + bl;
    const int t = threadIdx.x;
    const int p = t & 63;
    const int g = t >> 6;

    float2 Zd[8], Zc[8];
    #pragma unroll
    for (int k20 = 0; k20 < 8; ++k20) {
        int m = k1 + 64 * k20;
        size_t off = ((size_t)m * BB + bat) * CC + ct * 128 + 2 * p;
        float2 a = __half22float2(*(const __half2*)(gre + off));
        float2 c = __half22float2(*(const __half2*)(gim + off));
        Zd[k20] = make_float2(a.x - c.y, c.x + a.y);
        int mp = 512 - k1 - 64 * k20;
        if (mp != 512) {
            size_t offp = ((size_t)mp * BB + bat) * CC + ct * 128 + 2 * p;
            float2 ap = __half22float2(*(const __half2*)(gre + offp));
            float2 cp = __half22float2(*(const __half2*)(gim + offp));
            Zc[k20] = make_float2(ap.x + cp.y, ap.y - cp.x);
        } else {
            Zc[k20] = make_float2(0.f, 0.f);
        }
    }

    __half2* tb = tbuf + (size_t)bl * (64 * 64 * 128) + (size_t)k1 * 128 + ct * 64 + p;
    #pragma unroll
    for (int s = 0; s < 2; ++s) {
        const int bd = g + 4 * s;
        float w8s, w8c;
        __sincosf(-PI_4 * (float)bd, &w8s, &w8c);   // e^{-i pi bd/4}
        float2 u[8];
        #pragma unroll
        for (int k20 = 0; k20 < 8; ++k20)
            u[k20] = cadd(Zd[k20], cmulf(Zc[k20], make_float2(w8c, w8s)));
        twid7(u, PI2_64 * (float)bd);               // e^{+i 2pi bd k20/64}
        dif8<-1>(u);                                // t[8a+bd] at index a
        float bs, bc, ss, sc;
        __sincosf(PI2_4096 * (float)(bd * k1), &bs, &bc);
        __sincosf(PI2_512 * (float)k1, &ss, &sc);
        float2 cur = make_float2(bc, bs), stp = make_float2(sc, ss);
        #pragma unroll
        for (int a = 0; a < 8; ++a) {
            float2 r = cmulf(u[a], cur);
            tb[(size_t)(8 * a + bd) * (64 * 128)] = __floats2half2_rn(r.x, r.y);
            cur = cmulf(cur, stp);
        }
    }
}

// ---------------- K3b ----------------
__global__ __launch_bounds__(256) void k3b_kernel(const __half2* __restrict__ tbuf,
                                                  const float* __restrict__ v,
                                                  float* __restrict__ out, int b0) {
    __shared__ float2 T[64 * 65];
    const int blk = blockIdx.x;
    const int ct = blk & 1;
    const int n2 = (blk >> 1) & 63;
    const int bl = blk >> 7;
    const int bat = b0 + bl;
    const int t = threadIdx.x;
    const int p = t & 63;
    const int g = t >> 6;

    const __half2* tb = tbuf + (size_t)bl * (64 * 64 * 128) + (size_t)n2 * (64 * 128) + ct * 64 + p;
    float2 X[2][8];
    #pragma unroll
    for (int s = 0; s < 2; ++s) {
        const int be = g + 4 * s;
        #pragma unroll
        for (int a = 0; a < 8; ++a)
            X[s][a] = __half22float2(tb[(size_t)(8 * a + be) * 128]);
    }
    #pragma unroll
    for (int s = 0; s < 2; ++s) {
        const int be = g + 4 * s;
        dif8<-1>(X[s]);
        twid7(X[s], PI2_64 * (float)be);            // e^{+i 2pi be j0/64}
        float2* row = T + p * 65;
        #pragma unroll
        for (int j0 = 0; j0 < 8; ++j0) row[be + 8 * j0] = X[s][j0];
    }
    __syncthreads();

    const float sc = 1.0f / 4096.0f;
    const float* vb = v   + ((size_t)bat << 20) + (size_t)n2 * CC + ct * 128 + 2 * p;
    float*       ob = out + ((size_t)bat << 20) + (size_t)n2 * CC + ct * 128 + 2 * p;
    #pragma unroll
    for (int s = 0; s < 2; ++s) {
        const int j0 = g + 4 * s;
        float2 r[8];
        const float2* row = T + p * 65 + 8 * j0;
        #pragma unroll
        for (int b = 0; b < 8; ++b) r[b] = row[b];
        dif8<-1>(r);                                // x[j0 + 8*j1] at index j1
        #pragma unroll
        for (int j1 = 0; j1 < 8; ++j1) {
            int n1 = j0 + 8 * j1;
            size_t off = (size_t)n1 * 16384;
            float2 vz = *(const float2*)(vb + off);
            float2 o = make_float2(vz.x + r[j1].x * sc, vz.y + r[j1].y * sc);
            *(float2*)(ob + off) = o;
        }
    }
}

extern "C" void kernel_launch(void* const* d_in, const int* in_sizes, int n_in,
                              void* d_out, int out_size, void* d_ws, size_t ws_size,
                              hipStream_t stream) {
    const float* v = (const float*)d_in[0];
    const float* R = (const float*)d_in[1];
    float* out = (float*)d_out;

    __half2* ybuf = (__half2*)d_ws;                               // 16*64*64*128 h2 = 33.5 MB (also tbuf)
    __half2* zbuf = ybuf + (size_t)16 * 64 * 64 * 128;            // 32*64*16*128 h2 = 16.8 MB
    __half*  gre  = (__half*)(zbuf + (size_t)32 * 64 * 16 * 128); // 8.4 MB
    __half*  gim  = gre + (size_t)MM * BB * CC;                   // 8.4 MB (total 64 MiB)

    for (int h = 0; h < 2; ++h) {
        k1a_kernel<<<2048, 256, 0, stream>>>(v, ybuf, h * 16);
        k1b_kernel<<<2048, 256, 0, stream>>>(ybuf, zbuf, h * 16);
    }
    k2_kernel<<<1024, 256, 0, stream>>>(zbuf, R, gre, gim);
    for (int h = 0; h < 2; ++h) {
        k3a_kernel<<<2048, 256, 0, stream>>>(gre, gim, ybuf, h * 16);
        k3b_kernel<<<2048, 256, 0, stream>>>(ybuf, v, out, h * 16);
    }
}